// Round 7
// baseline (313.081 us; speedup 1.0000x reference)
//
#include <hip/hip_runtime.h>
#include <math.h>

// Problem constants
constexpr int B_  = 2;
constexpr int C_  = 256;
constexpr int CQ_ = 64;
constexpr int N_  = 4096;  // 64*64

typedef __attribute__((ext_vector_type(8))) short     short8;  // 8 bf16
typedef __attribute__((ext_vector_type(8))) _Float16  half8;   // 8 f16
typedef __attribute__((ext_vector_type(4))) float     f32x4;   // MFMA C/D

constexpr float SHIFT = 24.0f;   // static softmax shift (exact: shift-invariance)

static __device__ __forceinline__ unsigned short f2bf(float x) {
    union { float f; unsigned u; } v; v.f = x;
    unsigned r = (v.u + 0x7FFFu + ((v.u >> 16) & 1u)) >> 16;  // RNE
    return (unsigned short)r;
}
static __device__ __forceinline__ unsigned short f2h(float x) {
    _Float16 h = (_Float16)x;
    return *(unsigned short*)&h;
}
static __device__ __forceinline__ half8 cvt_w8(const float* p) {
    float4 f0 = *(const float4*)p;
    float4 f1 = *(const float4*)(p + 4);
    half8 h;
    h[0] = (_Float16)f0.x; h[1] = (_Float16)f0.y;
    h[2] = (_Float16)f0.z; h[3] = (_Float16)f0.w;
    h[4] = (_Float16)f1.x; h[5] = (_Float16)f1.y;
    h[6] = (_Float16)f1.z; h[7] = (_Float16)f1.w;
    return h;
}

// ---------------------------------------------------------------------------
// Fused QKV projection (MFMA, f16, fp32 accum).  W converted on the fly
// (L2-hot).  Per block: one 64-n tile of one bs; z=0 -> Q+K, z=1 -> V.
// ---------------------------------------------------------------------------
__global__ __launch_bounds__(512)
void proj_kernel(const float* __restrict__ in1, const float* __restrict__ in2,
                 const float* __restrict__ q1w, const float* __restrict__ q1b,
                 const float* __restrict__ k1w, const float* __restrict__ k1b,
                 const float* __restrict__ v1w, const float* __restrict__ v1b,
                 const float* __restrict__ q2w, const float* __restrict__ q2b,
                 const float* __restrict__ k2w, const float* __restrict__ k2b,
                 const float* __restrict__ v2w, const float* __restrict__ v2b,
                 _Float16* __restrict__ q_ws, _Float16* __restrict__ k_ws,
                 unsigned short* __restrict__ v_ws)
{
    __shared__ _Float16 Xs[64 * 264];
    const int bs = blockIdx.y, s = bs >> 1, bb = bs & 1;
    const int n0 = blockIdx.x * 64;
    const float* x = (s ? in2 : in1) + (size_t)bb * C_ * N_;
    const int tid = threadIdx.x;
    const int lane = tid & 63, wave = tid >> 6, quad = lane >> 4, l15 = lane & 15;

    // stage + transpose + convert X tile (256c x 64n) -> Xs[n][c] f16
    #pragma unroll
    for (int rep = 0; rep < 8; ++rep) {
        int idx = rep * 512 + tid;
        int c = idx >> 4, ng = idx & 15;
        float4 f = *(const float4*)(x + (size_t)c * N_ + n0 + ng * 4);
        Xs[(ng * 4 + 0) * 264 + c] = (_Float16)f.x;
        Xs[(ng * 4 + 1) * 264 + c] = (_Float16)f.y;
        Xs[(ng * 4 + 2) * 264 + c] = (_Float16)f.z;
        Xs[(ng * 4 + 3) * 264 + c] = (_Float16)f.w;
    }
    __syncthreads();

    if (blockIdx.z == 0) {
        // ---- Q/K: waves 0-3 -> Q (nb=wave), waves 4-7 -> K ----
        const int m = wave >> 2, nb = wave & 3;
        const float* W    = m ? (s ? k2w : k1w) : (s ? q2w : q1w);
        const float* bias = m ? (s ? k2b : k1b) : (s ? q2b : q1b);
        _Float16* outp = (m ? k_ws : q_ws) + (size_t)bs * N_ * CQ_;

        half8 bfx[8];
        #pragma unroll
        for (int kh = 0; kh < 8; ++kh)
            bfx[kh] = *(const half8*)(&Xs[(16 * nb + l15) * 264 + quad * 8 + kh * 32]);
        f32x4 acc[4];
        #pragma unroll
        for (int o = 0; o < 4; ++o) acc[o] = (f32x4){0.f, 0.f, 0.f, 0.f};
        #pragma unroll
        for (int kh = 0; kh < 8; ++kh)
            #pragma unroll
            for (int o = 0; o < 4; ++o) {
                half8 aw = cvt_w8(W + (size_t)(16 * o + l15) * C_ + quad * 8 + kh * 32);
                acc[o] = __builtin_amdgcn_mfma_f32_16x16x32_f16(aw, bfx[kh], acc[o], 0, 0, 0);
            }
        int n = n0 + 16 * nb + l15;
        #pragma unroll
        for (int o = 0; o < 4; ++o) {
            float4 bv = *(const float4*)(bias + 16 * o + quad * 4);
            ushort4 u;
            u.x = f2h(acc[o][0] + bv.x); u.y = f2h(acc[o][1] + bv.y);
            u.z = f2h(acc[o][2] + bv.z); u.w = f2h(acc[o][3] + bv.w);
            *(ushort4*)((unsigned short*)outp + (size_t)n * CQ_ + 16 * o + quad * 4) = u;
        }
    } else {
        // ---- V: wave owns c-rows 32*wave .. +31 ----
        const float* Wv = (s ? v2w : v1w);
        const float* vb = (s ? v2b : v1b);
        unsigned short* outp = v_ws + (size_t)bs * C_ * N_;
        f32x4 acc[4][2];
        #pragma unroll
        for (int nt = 0; nt < 4; ++nt)
            #pragma unroll
            for (int oo = 0; oo < 2; ++oo) acc[nt][oo] = (f32x4){0.f, 0.f, 0.f, 0.f};
        #pragma unroll
        for (int kh = 0; kh < 8; ++kh) {
            half8 af[4], bw[2];
            #pragma unroll
            for (int nt = 0; nt < 4; ++nt)
                af[nt] = *(const half8*)(&Xs[(16 * nt + l15) * 264 + quad * 8 + kh * 32]);
            #pragma unroll
            for (int oo = 0; oo < 2; ++oo)
                bw[oo] = cvt_w8(Wv + (size_t)(32 * wave + 16 * oo + l15) * C_ + quad * 8 + kh * 32);
            #pragma unroll
            for (int nt = 0; nt < 4; ++nt)
                #pragma unroll
                for (int oo = 0; oo < 2; ++oo)
                    acc[nt][oo] = __builtin_amdgcn_mfma_f32_16x16x32_f16(
                        af[nt], bw[oo], acc[nt][oo], 0, 0, 0);
        }
        #pragma unroll
        for (int oo = 0; oo < 2; ++oo) {
            int c = 32 * wave + 16 * oo + l15;
            float bv = vb[c];
            #pragma unroll
            for (int nt = 0; nt < 4; ++nt) {
                ushort4 u;
                u.x = f2bf(acc[nt][oo][0] + bv);
                u.y = f2bf(acc[nt][oo][1] + bv);
                u.z = f2bf(acc[nt][oo][2] + bv);
                u.w = f2bf(acc[nt][oo][3] + bv);
                *(ushort4*)(outp + (size_t)c * N_ + n0 + 16 * nt + quad * 4) = u;
            }
        }
    }
}

// ---------------------------------------------------------------------------
// MFMA flash attention, static-shift softmax (exact: shift-invariance; the
// gating bias is constant along the softmax axis -> cancels, skipped).
// 1024 thr / 16 waves per WG, grid 256 (1 WG/CU, 4 waves/SIMD).
// Per iter (64 j):
//   S role (jb=w&3, ihq=w>>2): S^T 16j x 16i; A=K-frag (global, pipelined in
//     regs), B=Q-frag (persistent).  p=exp(s-SHIFT) -> bf16 -> XOR-swizzled
//     double-buffered LDS.  l accumulated per-thread.
//   barrier: raw "s_waitcnt lgkmcnt(0); s_barrier" (no vmcnt drain; next
//     iter's K/V loads stay in flight).
//   PV role (wc=w&7, ih2=w>>3): O^T 32i x 32c; A=P (LDS, conflict-free),
//     B=V-frag (global, pipelined).  V enters the CU exactly once per iter.
// ---------------------------------------------------------------------------
__global__ __launch_bounds__(1024, 4)
void flash_kernel(const _Float16* __restrict__ qg,        // [bs][n][64] f16
                  const _Float16* __restrict__ kg,        // [bs][n][64] f16
                  const unsigned short* __restrict__ vg,  // [bs][c][n] bf16
                  const float* __restrict__ in1, const float* __restrict__ in2,
                  const float* __restrict__ gamma_p, float* __restrict__ out)
{
    __shared__ unsigned short Pt[2][64 * 64];   // [i][j], 16B-chunk ^ (i&7)
    __shared__ float lsum[64 * 4];

    const int tid  = threadIdx.x;
    const int lane = tid & 63;
    const int wave = tid >> 6;                  // 0..15
    const int quad = lane >> 4;
    const int l15  = lane & 15;
    const int bs   = blockIdx.x & 3;            // XCD L2 affinity
    const int q0   = (blockIdx.x >> 2) * 64;
    const int s = bs >> 1, bb = bs & 1;
    const int jb  = wave & 3,  ihq = wave >> 2; // S role
    const int wc  = wave & 7,  ih2 = wave >> 3; // PV role

    const _Float16* qp = qg + (size_t)bs * N_ * CQ_;
    const _Float16* kp = kg + (size_t)bs * N_ * CQ_;
    const unsigned short* vp = vg + (size_t)bs * C_ * N_;

    // persistent Q B-frags (col i = q0 + 16*ihq + l15)
    half8 qf[2];
    #pragma unroll
    for (int kh = 0; kh < 2; ++kh)
        qf[kh] = *(const half8*)(qp + (size_t)(q0 + 16 * ihq + l15) * CQ_ + quad * 8 + kh * 32);

    // pipelined K A-frags (j = 16*jb + l15) and V B-frags (c = 32*wc+16csub+l15)
    half8 kf[2];
    #pragma unroll
    for (int kh = 0; kh < 2; ++kh)
        kf[kh] = *(const half8*)(kp + (size_t)(16 * jb + l15) * CQ_ + quad * 8 + kh * 32);
    short8 vf[2][2];
    #pragma unroll
    for (int csub = 0; csub < 2; ++csub)
        #pragma unroll
        for (int kh = 0; kh < 2; ++kh)
            vf[csub][kh] = *(const short8*)(
                vp + (size_t)(32 * wc + 16 * csub + l15) * N_ + quad * 8 + kh * 32);

    float lacc = 0.f;
    f32x4 acc[2][2];   // [isub: i=32ih2+16isub+quad*4+r][csub: c=32wc+16csub+l15]
    #pragma unroll
    for (int a = 0; a < 2; ++a)
        #pragma unroll
        for (int b = 0; b < 2; ++b) acc[a][b] = (f32x4){0.f, 0.f, 0.f, 0.f};

    for (int t = 0; t < 64; ++t) {
        const int jn = (t + 1 < 64) ? (t + 1) * 64 : 0;
        // issue next-tile loads (consumed next iter; fly across the barrier)
        half8 kn[2];
        #pragma unroll
        for (int kh = 0; kh < 2; ++kh)
            kn[kh] = *(const half8*)(
                kp + (size_t)(jn + 16 * jb + l15) * CQ_ + quad * 8 + kh * 32);
        short8 vn[2][2];
        #pragma unroll
        for (int csub = 0; csub < 2; ++csub)
            #pragma unroll
            for (int kh = 0; kh < 2; ++kh)
                vn[csub][kh] = *(const short8*)(
                    vp + (size_t)(32 * wc + 16 * csub + l15) * N_ + jn + quad * 8 + kh * 32);

        // ---- S: S^T[j=16jb+quad*4+r][i=16ihq+l15] ----
        f32x4 sacc = (f32x4){0.f, 0.f, 0.f, 0.f};
        sacc = __builtin_amdgcn_mfma_f32_16x16x32_f16(kf[0], qf[0], sacc, 0, 0, 0);
        sacc = __builtin_amdgcn_mfma_f32_16x16x32_f16(kf[1], qf[1], sacc, 0, 0, 0);

        // p = exp(s-SHIFT) -> bf16 -> swizzled LDS; accumulate l per-thread
        unsigned short* Pb = Pt[t & 1];
        {
            f32x4 p;
            p.x = __expf(sacc.x - SHIFT);
            p.y = __expf(sacc.y - SHIFT);
            p.z = __expf(sacc.z - SHIFT);
            p.w = __expf(sacc.w - SHIFT);
            lacc += p.x + p.y + p.z + p.w;
            ushort4 pb;
            pb.x = f2bf(p.x); pb.y = f2bf(p.y); pb.z = f2bf(p.z); pb.w = f2bf(p.w);
            int row = 16 * ihq + l15;
            int off = row * 64 + (((2 * jb + (quad >> 1)) ^ (row & 7)) << 3)
                    + ((quad & 1) << 2);
            *(ushort4*)(&Pb[off]) = pb;
        }

        // LDS-only barrier: no vmcnt drain (K/V prefetch stays in flight)
        asm volatile("s_waitcnt lgkmcnt(0)\n\ts_barrier" ::: "memory");

        // ---- PV: O^T[i=32ih2+16isub+quad*4+r][c=32wc+16csub+l15] ----
        short8 ap[2][2];
        #pragma unroll
        for (int isub = 0; isub < 2; ++isub)
            #pragma unroll
            for (int kh = 0; kh < 2; ++kh) {
                int row = 32 * ih2 + 16 * isub + l15;
                ap[isub][kh] = *(const short8*)(
                    &Pb[row * 64 + (((quad + 4 * kh) ^ (row & 7)) << 3)]);
            }
        #pragma unroll
        for (int kh = 0; kh < 2; ++kh)
            #pragma unroll
            for (int isub = 0; isub < 2; ++isub)
                #pragma unroll
                for (int csub = 0; csub < 2; ++csub)
                    acc[isub][csub] = __builtin_amdgcn_mfma_f32_16x16x32_bf16(
                        ap[isub][kh], vf[csub][kh], acc[isub][csub], 0, 0, 0);

        kf[0] = kn[0]; kf[1] = kn[1];
        #pragma unroll
        for (int csub = 0; csub < 2; ++csub)
            #pragma unroll
            for (int kh = 0; kh < 2; ++kh) vf[csub][kh] = vn[csub][kh];
    }

    // ---- l reduction (once): i = 16*ihq + l15, partial over 16 j of jb ----
    {
        float tq = lacc;
        tq += __shfl_xor(tq, 16);
        tq += __shfl_xor(tq, 32);
        if (quad == 0) lsum[(16 * ihq + l15) * 4 + jb] = tq;
    }
    __syncthreads();

    const float gamma = gamma_p[0];
    const float* inp = (s ? in2 : in1) + (size_t)bb * C_ * N_;
    float* op = out + (size_t)bs * C_ * N_;
    #pragma unroll
    for (int isub = 0; isub < 2; ++isub) {
        float inv[4];
        #pragma unroll
        for (int r = 0; r < 4; ++r) {
            f32x4 tl = *(f32x4*)(&lsum[(32 * ih2 + 16 * isub + quad * 4 + r) * 4]);
            inv[r] = gamma / (tl.x + tl.y + tl.z + tl.w);
        }
        #pragma unroll
        for (int csub = 0; csub < 2; ++csub) {
            int c = 32 * wc + 16 * csub + l15;
            int i0 = q0 + 32 * ih2 + 16 * isub + quad * 4;
            float4 ip = *(const float4*)(inp + (size_t)c * N_ + i0);
            float4 o4;
            o4.x = acc[isub][csub][0] * inv[0] + ip.x;
            o4.y = acc[isub][csub][1] * inv[1] + ip.y;
            o4.z = acc[isub][csub][2] * inv[2] + ip.z;
            o4.w = acc[isub][csub][3] * inv[3] + ip.w;
            *(float4*)(op + (size_t)c * N_ + i0) = o4;
        }
    }
}

// ---------------------------------------------------------------------------
extern "C" void kernel_launch(void* const* d_in, const int* in_sizes, int n_in,
                              void* d_out, int out_size, void* d_ws, size_t ws_size,
                              hipStream_t stream)
{
    const float* in1 = (const float*)d_in[0];
    const float* in2 = (const float*)d_in[1];
    const float* q1w = (const float*)d_in[2];
    const float* q1b = (const float*)d_in[3];
    const float* k1w = (const float*)d_in[4];
    const float* k1b = (const float*)d_in[5];
    const float* v1w = (const float*)d_in[6];
    const float* v1b = (const float*)d_in[7];
    const float* q2w = (const float*)d_in[8];
    const float* q2b = (const float*)d_in[9];
    const float* k2w = (const float*)d_in[10];
    const float* k2b = (const float*)d_in[11];
    const float* v2w = (const float*)d_in[12];
    const float* v2b = (const float*)d_in[13];
    const float* gamma = (const float*)d_in[22];
    float* out = (float*)d_out;

    // ws: q[4][4096][64] f16 | k same | v[4][256][4096] bf16  (12 MB)
    _Float16* q_ws = (_Float16*)d_ws;
    _Float16* k_ws = q_ws + (size_t)4 * N_ * CQ_;
    unsigned short* v_ws = (unsigned short*)(k_ws + (size_t)4 * N_ * CQ_);

    proj_kernel<<<dim3(64, 4, 2), 512, 0, stream>>>(
        in1, in2, q1w, q1b, k1w, k1b, v1w, v1b,
        q2w, q2b, k2w, k2b, v2w, v2b, q_ws, k_ws, v_ws);
    flash_kernel<<<dim3(256), 1024, 0, stream>>>(q_ws, k_ws, v_ws, in1, in2, gamma, out);
}

// Round 8
// 236.060 us; speedup vs baseline: 1.3263x; 1.3263x over previous
//
#include <hip/hip_runtime.h>
#include <math.h>

// Problem constants
constexpr int B_  = 2;
constexpr int C_  = 256;
constexpr int CQ_ = 64;
constexpr int N_  = 4096;  // 64*64
constexpr int CN  = C_ * N_;   // 1048576

typedef __attribute__((ext_vector_type(8))) short     short8;  // 8 bf16
typedef __attribute__((ext_vector_type(8))) _Float16  half8;   // 8 f16
typedef __attribute__((ext_vector_type(4))) float     f32x4;   // MFMA C/D

constexpr float SHIFT = 24.0f;   // static softmax shift (exact: shift-invariance)

static __device__ __forceinline__ unsigned short f2bf(float x) {
    union { float f; unsigned u; } v; v.f = x;
    unsigned r = (v.u + 0x7FFFu + ((v.u >> 16) & 1u)) >> 16;  // RNE
    return (unsigned short)r;
}
static __device__ __forceinline__ unsigned short f2h(float x) {
    _Float16 h = (_Float16)x;
    return *(unsigned short*)&h;
}
static __device__ __forceinline__ half8 cvt_w8(const float* p) {
    float4 f0 = *(const float4*)p;
    float4 f1 = *(const float4*)(p + 4);
    half8 h;
    h[0] = (_Float16)f0.x; h[1] = (_Float16)f0.y;
    h[2] = (_Float16)f0.z; h[3] = (_Float16)f0.w;
    h[4] = (_Float16)f1.x; h[5] = (_Float16)f1.y;
    h[6] = (_Float16)f1.z; h[7] = (_Float16)f1.w;
    return h;
}

// ---------------------------------------------------------------------------
// Fused QKV projection (MFMA, f16, fp32 accum).  W converted on the fly
// (L2-hot).  Per block: one 64-n tile of one bs; z=0 -> Q+K, z=1 -> V.
// ---------------------------------------------------------------------------
__global__ __launch_bounds__(512)
void proj_kernel(const float* __restrict__ in1, const float* __restrict__ in2,
                 const float* __restrict__ q1w, const float* __restrict__ q1b,
                 const float* __restrict__ k1w, const float* __restrict__ k1b,
                 const float* __restrict__ v1w, const float* __restrict__ v1b,
                 const float* __restrict__ q2w, const float* __restrict__ q2b,
                 const float* __restrict__ k2w, const float* __restrict__ k2b,
                 const float* __restrict__ v2w, const float* __restrict__ v2b,
                 _Float16* __restrict__ q_ws, _Float16* __restrict__ k_ws,
                 unsigned short* __restrict__ v_ws)
{
    __shared__ _Float16 Xs[64 * 264];
    const int bs = blockIdx.y, s = bs >> 1, bb = bs & 1;
    const int n0 = blockIdx.x * 64;
    const float* x = (s ? in2 : in1) + (size_t)bb * CN;
    const int tid = threadIdx.x;
    const int lane = tid & 63, wave = tid >> 6, quad = lane >> 4, l15 = lane & 15;

    // stage + transpose + convert X tile (256c x 64n) -> Xs[n][c] f16
    #pragma unroll
    for (int rep = 0; rep < 8; ++rep) {
        int idx = rep * 512 + tid;
        int c = idx >> 4, ng = idx & 15;
        float4 f = *(const float4*)(x + (size_t)c * N_ + n0 + ng * 4);
        Xs[(ng * 4 + 0) * 264 + c] = (_Float16)f.x;
        Xs[(ng * 4 + 1) * 264 + c] = (_Float16)f.y;
        Xs[(ng * 4 + 2) * 264 + c] = (_Float16)f.z;
        Xs[(ng * 4 + 3) * 264 + c] = (_Float16)f.w;
    }
    __syncthreads();

    if (blockIdx.z == 0) {
        // ---- Q/K: waves 0-3 -> Q (nb=wave), waves 4-7 -> K ----
        const int m = wave >> 2, nb = wave & 3;
        const float* W    = m ? (s ? k2w : k1w) : (s ? q2w : q1w);
        const float* bias = m ? (s ? k2b : k1b) : (s ? q2b : q1b);
        _Float16* outp = (m ? k_ws : q_ws) + (size_t)bs * N_ * CQ_;

        half8 bfx[8];
        #pragma unroll
        for (int kh = 0; kh < 8; ++kh)
            bfx[kh] = *(const half8*)(&Xs[(16 * nb + l15) * 264 + quad * 8 + kh * 32]);
        f32x4 acc[4];
        #pragma unroll
        for (int o = 0; o < 4; ++o) acc[o] = (f32x4){0.f, 0.f, 0.f, 0.f};
        #pragma unroll
        for (int kh = 0; kh < 8; ++kh)
            #pragma unroll
            for (int o = 0; o < 4; ++o) {
                half8 aw = cvt_w8(W + (size_t)(16 * o + l15) * C_ + quad * 8 + kh * 32);
                acc[o] = __builtin_amdgcn_mfma_f32_16x16x32_f16(aw, bfx[kh], acc[o], 0, 0, 0);
            }
        int n = n0 + 16 * nb + l15;
        #pragma unroll
        for (int o = 0; o < 4; ++o) {
            float4 bv = *(const float4*)(bias + 16 * o + quad * 4);
            ushort4 u;
            u.x = f2h(acc[o][0] + bv.x); u.y = f2h(acc[o][1] + bv.y);
            u.z = f2h(acc[o][2] + bv.z); u.w = f2h(acc[o][3] + bv.w);
            *(ushort4*)((unsigned short*)outp + (size_t)n * CQ_ + 16 * o + quad * 4) = u;
        }
    } else {
        // ---- V: wave owns c-rows 32*wave .. +31 ----
        const float* Wv = (s ? v2w : v1w);
        const float* vb = (s ? v2b : v1b);
        unsigned short* outp = v_ws + (size_t)bs * CN;
        f32x4 acc[4][2];
        #pragma unroll
        for (int nt = 0; nt < 4; ++nt)
            #pragma unroll
            for (int oo = 0; oo < 2; ++oo) acc[nt][oo] = (f32x4){0.f, 0.f, 0.f, 0.f};
        #pragma unroll
        for (int kh = 0; kh < 8; ++kh) {
            half8 af[4], bw[2];
            #pragma unroll
            for (int nt = 0; nt < 4; ++nt)
                af[nt] = *(const half8*)(&Xs[(16 * nt + l15) * 264 + quad * 8 + kh * 32]);
            #pragma unroll
            for (int oo = 0; oo < 2; ++oo)
                bw[oo] = cvt_w8(Wv + (size_t)(32 * wave + 16 * oo + l15) * C_ + quad * 8 + kh * 32);
            #pragma unroll
            for (int nt = 0; nt < 4; ++nt)
                #pragma unroll
                for (int oo = 0; oo < 2; ++oo)
                    acc[nt][oo] = __builtin_amdgcn_mfma_f32_16x16x32_f16(
                        af[nt], bw[oo], acc[nt][oo], 0, 0, 0);
        }
        #pragma unroll
        for (int oo = 0; oo < 2; ++oo) {
            int c = 32 * wave + 16 * oo + l15;
            float bv = vb[c];
            #pragma unroll
            for (int nt = 0; nt < 4; ++nt) {
                ushort4 u;
                u.x = f2bf(acc[nt][oo][0] + bv);
                u.y = f2bf(acc[nt][oo][1] + bv);
                u.z = f2bf(acc[nt][oo][2] + bv);
                u.w = f2bf(acc[nt][oo][3] + bv);
                *(ushort4*)(outp + (size_t)c * N_ + n0 + 16 * nt + quad * 4) = u;
            }
        }
    }
}

// ---------------------------------------------------------------------------
// MFMA flash attention, static-shift softmax, j-SPLIT partials.
// Exactness: softmax shift-invariance (static SHIFT); the gating bias is
// constant along the softmax axis -> cancels; with a GLOBAL shift, partial
// (unnormalized O, l) over disjoint j-ranges merge by pure addition.
// grid 512 = 4 bs x 64 q-tiles x 2 j-splits -> 2 WG/CU with INDEPENDENT
// barriers and NO K/V traffic duplication (each WG sweeps its own j half).
// 8 waves/WG.  Per iter (64 j):
//   S (jb=w&3, ih=w>>2): S^T 16j x 32i; A=K-frag, B=Q-frag (regs, pipelined).
//   exp -> bf16 P -> XOR-swizzled double-buffered LDS.
//   barrier = raw "s_waitcnt lgkmcnt(0); s_barrier" (no vmcnt drain).
//   PV (wc=w): O^T 64i x 32c; A=P (LDS), B=V-frag (global, pipelined).
// split0 writes raw fp32 O into d_out, split1 into part1; l into lp[split].
// ---------------------------------------------------------------------------
__global__ __launch_bounds__(512, 4)
void flash_kernel(const _Float16* __restrict__ qg,        // [bs][n][64] f16
                  const _Float16* __restrict__ kg,        // [bs][n][64] f16
                  const unsigned short* __restrict__ vg,  // [bs][c][n] bf16
                  float* __restrict__ out,                // split0 partial O
                  float* __restrict__ part1,              // split1 partial O
                  float* __restrict__ lp)                 // [2][4][4096]
{
    __shared__ unsigned short Pt[2][64 * 64];   // [i][j], 16B-chunk ^ (i&7)
    __shared__ float lsum[64 * 4];

    const int tid  = threadIdx.x;
    const int lane = tid & 63;
    const int wave = tid >> 6;                  // 0..7
    const int quad = lane >> 4;
    const int l15  = lane & 15;
    const int blk  = blockIdx.x;
    const int bs   = blk & 3;                   // XCD L2 affinity
    const int split = (blk >> 2) & 1;
    const int q0   = (blk >> 3) * 64;
    const int jbase = split * 2048;
    const int jb = wave & 3, ih = wave >> 2;    // S role
    const int wc = wave;                        // PV role: c-block 32*wc

    const _Float16* qp = qg + (size_t)bs * N_ * CQ_;
    const _Float16* kp = kg + (size_t)bs * N_ * CQ_;
    const unsigned short* vp = vg + (size_t)bs * CN;

    // persistent Q B-frags (col i = q0 + 32ih + 16isub + l15)
    half8 qf[2][2];
    #pragma unroll
    for (int isub = 0; isub < 2; ++isub)
        #pragma unroll
        for (int kh = 0; kh < 2; ++kh)
            qf[isub][kh] = *(const half8*)(
                qp + (size_t)(q0 + 32 * ih + 16 * isub + l15) * CQ_ + quad * 8 + kh * 32);

    // pipelined K A-frags (j = jbase+16jb+l15), V B-frags (c = 32wc+16csub+l15)
    half8 kf[2];
    #pragma unroll
    for (int kh = 0; kh < 2; ++kh)
        kf[kh] = *(const half8*)(
            kp + (size_t)(jbase + 16 * jb + l15) * CQ_ + quad * 8 + kh * 32);
    short8 vf[2][2];
    #pragma unroll
    for (int csub = 0; csub < 2; ++csub)
        #pragma unroll
        for (int kh = 0; kh < 2; ++kh)
            vf[csub][kh] = *(const short8*)(
                vp + (size_t)(32 * wc + 16 * csub + l15) * N_ + jbase + quad * 8 + kh * 32);

    float lacc[2] = {0.f, 0.f};
    f32x4 acc[4][2];   // [isub: i=16isub+quad*4+r][csub: c=32wc+16csub+l15]
    #pragma unroll
    for (int a = 0; a < 4; ++a)
        #pragma unroll
        for (int b = 0; b < 2; ++b) acc[a][b] = (f32x4){0.f, 0.f, 0.f, 0.f};

    for (int t = 0; t < 32; ++t) {
        const int jt = jbase + t * 64;
        const int jn = (t + 1 < 32) ? jt + 64 : jbase;
        // issue next-tile loads (consumed next iter; fly across the barrier)
        half8 kn[2];
        #pragma unroll
        for (int kh = 0; kh < 2; ++kh)
            kn[kh] = *(const half8*)(
                kp + (size_t)(jn + 16 * jb + l15) * CQ_ + quad * 8 + kh * 32);
        short8 vn[2][2];
        #pragma unroll
        for (int csub = 0; csub < 2; ++csub)
            #pragma unroll
            for (int kh = 0; kh < 2; ++kh)
                vn[csub][kh] = *(const short8*)(
                    vp + (size_t)(32 * wc + 16 * csub + l15) * N_ + jn + quad * 8 + kh * 32);

        // ---- S: S^T[j=16jb+quad*4+r][i=32ih+16isub+l15] ----
        f32x4 sacc[2];
        sacc[0] = (f32x4){0.f, 0.f, 0.f, 0.f};
        sacc[1] = (f32x4){0.f, 0.f, 0.f, 0.f};
        #pragma unroll
        for (int kh = 0; kh < 2; ++kh)
            #pragma unroll
            for (int isub = 0; isub < 2; ++isub)
                sacc[isub] = __builtin_amdgcn_mfma_f32_16x16x32_f16(
                    kf[kh], qf[isub][kh], sacc[isub], 0, 0, 0);

        // p = exp(s-SHIFT) -> bf16 -> swizzled LDS; accumulate l per-thread
        unsigned short* Pb = Pt[t & 1];
        #pragma unroll
        for (int isub = 0; isub < 2; ++isub) {
            f32x4 p;
            p.x = __expf(sacc[isub].x - SHIFT);
            p.y = __expf(sacc[isub].y - SHIFT);
            p.z = __expf(sacc[isub].z - SHIFT);
            p.w = __expf(sacc[isub].w - SHIFT);
            lacc[isub] += p.x + p.y + p.z + p.w;
            ushort4 pb;
            pb.x = f2bf(p.x); pb.y = f2bf(p.y); pb.z = f2bf(p.z); pb.w = f2bf(p.w);
            int row = 32 * ih + 16 * isub + l15;
            int off = row * 64 + (((2 * jb + (quad >> 1)) ^ (row & 7)) << 3)
                    + ((quad & 1) << 2);
            *(ushort4*)(&Pb[off]) = pb;
        }

        // LDS-only barrier: no vmcnt drain (K/V prefetch stays in flight)
        asm volatile("s_waitcnt lgkmcnt(0)\n\ts_barrier" ::: "memory");

        // ---- PV: O^T[i=16isub+quad*4+r][c=32wc+16csub+l15] ----
        short8 ap[4][2];
        #pragma unroll
        for (int isub = 0; isub < 4; ++isub)
            #pragma unroll
            for (int kh = 0; kh < 2; ++kh) {
                int row = 16 * isub + l15;
                ap[isub][kh] = *(const short8*)(
                    &Pb[row * 64 + (((quad + 4 * kh) ^ (row & 7)) << 3)]);
            }
        #pragma unroll
        for (int kh = 0; kh < 2; ++kh)
            #pragma unroll
            for (int isub = 0; isub < 4; ++isub)
                #pragma unroll
                for (int csub = 0; csub < 2; ++csub)
                    acc[isub][csub] = __builtin_amdgcn_mfma_f32_16x16x32_bf16(
                        ap[isub][kh], vf[csub][kh], acc[isub][csub], 0, 0, 0);

        kf[0] = kn[0]; kf[1] = kn[1];
        #pragma unroll
        for (int csub = 0; csub < 2; ++csub)
            #pragma unroll
            for (int kh = 0; kh < 2; ++kh) vf[csub][kh] = vn[csub][kh];
    }

    // ---- partial l reduction ----
    #pragma unroll
    for (int isub = 0; isub < 2; ++isub) {
        float tq = lacc[isub];
        tq += __shfl_xor(tq, 16);
        tq += __shfl_xor(tq, 32);
        if (quad == 0) lsum[(32 * ih + 16 * isub + l15) * 4 + jb] = tq;
    }
    __syncthreads();
    if (tid < 64) {
        f32x4 tl = *(f32x4*)(&lsum[tid * 4]);
        lp[(size_t)(split * 4 + bs) * N_ + q0 + tid] = tl.x + tl.y + tl.z + tl.w;
    }

    // ---- raw partial-O store (fp32, unnormalized, no input add) ----
    float* pp = (split ? part1 : out) + (size_t)bs * CN;
    #pragma unroll
    for (int isub = 0; isub < 4; ++isub)
        #pragma unroll
        for (int csub = 0; csub < 2; ++csub) {
            int c = 32 * wc + 16 * csub + l15;
            int i0 = q0 + 16 * isub + quad * 4;
            f32x4 a = acc[isub][csub];
            float4 o4 = {a[0], a[1], a[2], a[3]};
            *(float4*)(pp + (size_t)c * N_ + i0) = o4;
        }
}

// ---------------------------------------------------------------------------
// Merge: out = gamma * (O0 + O1) / (l0 + l1) + input
// ---------------------------------------------------------------------------
__global__ __launch_bounds__(256)
void merge_kernel(const float* __restrict__ part1, const float* __restrict__ lp,
                  const float* __restrict__ in1, const float* __restrict__ in2,
                  const float* __restrict__ gamma_p, float* __restrict__ out)
{
    const int g = (blockIdx.x * 256 + threadIdx.x) * 4;   // grid 4096
    const int bs = g >> 20;                                // CN = 1<<20
    const int off = g & (CN - 1);
    const int i = g & (N_ - 1);
    const float gamma = gamma_p[0];
    float4 o0 = *(const float4*)(out + g);
    float4 p1 = *(const float4*)(part1 + g);
    float4 l0 = *(const float4*)(lp + (size_t)bs * N_ + i);
    float4 l1 = *(const float4*)(lp + (size_t)(4 + bs) * N_ + i);
    const float* inp = ((bs >> 1) ? in2 : in1) + (size_t)(bs & 1) * CN;
    float4 ip = *(const float4*)(inp + off);
    float4 r;
    r.x = gamma * (o0.x + p1.x) / (l0.x + l1.x) + ip.x;
    r.y = gamma * (o0.y + p1.y) / (l0.y + l1.y) + ip.y;
    r.z = gamma * (o0.z + p1.z) / (l0.z + l1.z) + ip.z;
    r.w = gamma * (o0.w + p1.w) / (l0.w + l1.w) + ip.w;
    *(float4*)(out + g) = r;
}

// ---------------------------------------------------------------------------
extern "C" void kernel_launch(void* const* d_in, const int* in_sizes, int n_in,
                              void* d_out, int out_size, void* d_ws, size_t ws_size,
                              hipStream_t stream)
{
    const float* in1 = (const float*)d_in[0];
    const float* in2 = (const float*)d_in[1];
    const float* q1w = (const float*)d_in[2];
    const float* q1b = (const float*)d_in[3];
    const float* k1w = (const float*)d_in[4];
    const float* k1b = (const float*)d_in[5];
    const float* v1w = (const float*)d_in[6];
    const float* v1b = (const float*)d_in[7];
    const float* q2w = (const float*)d_in[8];
    const float* q2b = (const float*)d_in[9];
    const float* k2w = (const float*)d_in[10];
    const float* k2b = (const float*)d_in[11];
    const float* v2w = (const float*)d_in[12];
    const float* v2b = (const float*)d_in[13];
    const float* gamma = (const float*)d_in[22];
    float* out = (float*)d_out;

    // ws: q 2MB f16 | k 2MB f16 | v 8MB bf16 | part1 16.8MB fp32 | lp 128KB
    _Float16* q_ws = (_Float16*)d_ws;
    _Float16* k_ws = q_ws + (size_t)4 * N_ * CQ_;
    unsigned short* v_ws = (unsigned short*)(k_ws + (size_t)4 * N_ * CQ_);
    float* part1 = (float*)(v_ws + (size_t)4 * CN);
    float* lp    = part1 + (size_t)4 * CN;

    proj_kernel<<<dim3(64, 4, 2), 512, 0, stream>>>(
        in1, in2, q1w, q1b, k1w, k1b, v1w, v1b,
        q2w, q2b, k2w, k2b, v2w, v2b, q_ws, k_ws, v_ws);
    flash_kernel<<<dim3(512), 512, 0, stream>>>(q_ws, k_ws, v_ws, out, part1, lp);
    merge_kernel<<<dim3(4096), 256, 0, stream>>>(part1, lp, in1, in2, gamma, out);
}

// Round 9
// 235.027 us; speedup vs baseline: 1.3321x; 1.0044x over previous
//
#include <hip/hip_runtime.h>
#include <math.h>

// Problem constants
constexpr int B_  = 2;
constexpr int C_  = 256;
constexpr int CQ_ = 64;
constexpr int N_  = 4096;  // 64*64
constexpr int CN  = C_ * N_;   // 1048576

typedef __attribute__((ext_vector_type(8))) short     short8;  // 8 bf16
typedef __attribute__((ext_vector_type(8))) _Float16  half8;   // 8 f16
typedef __attribute__((ext_vector_type(4))) float     f32x4;   // MFMA C/D

constexpr float SHIFT = 24.0f;   // static softmax shift (exact: shift-invariance)

static __device__ __forceinline__ unsigned short f2bf(float x) {
    union { float f; unsigned u; } v; v.f = x;
    unsigned r = (v.u + 0x7FFFu + ((v.u >> 16) & 1u)) >> 16;  // RNE
    return (unsigned short)r;
}
static __device__ __forceinline__ unsigned short f2h(float x) {
    _Float16 h = (_Float16)x;
    return *(unsigned short*)&h;
}
static __device__ __forceinline__ half8 cvt_w8(const float* p) {
    float4 f0 = *(const float4*)p;
    float4 f1 = *(const float4*)(p + 4);
    half8 h;
    h[0] = (_Float16)f0.x; h[1] = (_Float16)f0.y;
    h[2] = (_Float16)f0.z; h[3] = (_Float16)f0.w;
    h[4] = (_Float16)f1.x; h[5] = (_Float16)f1.y;
    h[6] = (_Float16)f1.z; h[7] = (_Float16)f1.w;
    return h;
}

// ---------------------------------------------------------------------------
// Fused QKV projection (MFMA, f16, fp32 accum).  W converted on the fly
// (L2-hot).  Per block: one 64-n tile of one bs; z=0 -> Q+K, z=1 -> V.
// ---------------------------------------------------------------------------
__global__ __launch_bounds__(512)
void proj_kernel(const float* __restrict__ in1, const float* __restrict__ in2,
                 const float* __restrict__ q1w, const float* __restrict__ q1b,
                 const float* __restrict__ k1w, const float* __restrict__ k1b,
                 const float* __restrict__ v1w, const float* __restrict__ v1b,
                 const float* __restrict__ q2w, const float* __restrict__ q2b,
                 const float* __restrict__ k2w, const float* __restrict__ k2b,
                 const float* __restrict__ v2w, const float* __restrict__ v2b,
                 _Float16* __restrict__ q_ws, _Float16* __restrict__ k_ws,
                 unsigned short* __restrict__ v_ws)
{
    __shared__ _Float16 Xs[64 * 264];
    const int bs = blockIdx.y, s = bs >> 1, bb = bs & 1;
    const int n0 = blockIdx.x * 64;
    const float* x = (s ? in2 : in1) + (size_t)bb * CN;
    const int tid = threadIdx.x;
    const int lane = tid & 63, wave = tid >> 6, quad = lane >> 4, l15 = lane & 15;

    // stage + transpose + convert X tile (256c x 64n) -> Xs[n][c] f16
    #pragma unroll
    for (int rep = 0; rep < 8; ++rep) {
        int idx = rep * 512 + tid;
        int c = idx >> 4, ng = idx & 15;
        float4 f = *(const float4*)(x + (size_t)c * N_ + n0 + ng * 4);
        Xs[(ng * 4 + 0) * 264 + c] = (_Float16)f.x;
        Xs[(ng * 4 + 1) * 264 + c] = (_Float16)f.y;
        Xs[(ng * 4 + 2) * 264 + c] = (_Float16)f.z;
        Xs[(ng * 4 + 3) * 264 + c] = (_Float16)f.w;
    }
    __syncthreads();

    if (blockIdx.z == 0) {
        // ---- Q/K: waves 0-3 -> Q (nb=wave), waves 4-7 -> K ----
        const int m = wave >> 2, nb = wave & 3;
        const float* W    = m ? (s ? k2w : k1w) : (s ? q2w : q1w);
        const float* bias = m ? (s ? k2b : k1b) : (s ? q2b : q1b);
        _Float16* outp = (m ? k_ws : q_ws) + (size_t)bs * N_ * CQ_;

        half8 bfx[8];
        #pragma unroll
        for (int kh = 0; kh < 8; ++kh)
            bfx[kh] = *(const half8*)(&Xs[(16 * nb + l15) * 264 + quad * 8 + kh * 32]);
        f32x4 acc[4];
        #pragma unroll
        for (int o = 0; o < 4; ++o) acc[o] = (f32x4){0.f, 0.f, 0.f, 0.f};
        #pragma unroll
        for (int kh = 0; kh < 8; ++kh)
            #pragma unroll
            for (int o = 0; o < 4; ++o) {
                half8 aw = cvt_w8(W + (size_t)(16 * o + l15) * C_ + quad * 8 + kh * 32);
                acc[o] = __builtin_amdgcn_mfma_f32_16x16x32_f16(aw, bfx[kh], acc[o], 0, 0, 0);
            }
        int n = n0 + 16 * nb + l15;
        #pragma unroll
        for (int o = 0; o < 4; ++o) {
            float4 bv = *(const float4*)(bias + 16 * o + quad * 4);
            ushort4 u;
            u.x = f2h(acc[o][0] + bv.x); u.y = f2h(acc[o][1] + bv.y);
            u.z = f2h(acc[o][2] + bv.z); u.w = f2h(acc[o][3] + bv.w);
            *(ushort4*)((unsigned short*)outp + (size_t)n * CQ_ + 16 * o + quad * 4) = u;
        }
    } else {
        // ---- V: wave owns c-rows 32*wave .. +31 ----
        const float* Wv = (s ? v2w : v1w);
        const float* vb = (s ? v2b : v1b);
        unsigned short* outp = v_ws + (size_t)bs * CN;
        f32x4 acc[4][2];
        #pragma unroll
        for (int nt = 0; nt < 4; ++nt)
            #pragma unroll
            for (int oo = 0; oo < 2; ++oo) acc[nt][oo] = (f32x4){0.f, 0.f, 0.f, 0.f};
        #pragma unroll
        for (int kh = 0; kh < 8; ++kh) {
            half8 af[4], bw[2];
            #pragma unroll
            for (int nt = 0; nt < 4; ++nt)
                af[nt] = *(const half8*)(&Xs[(16 * nt + l15) * 264 + quad * 8 + kh * 32]);
            #pragma unroll
            for (int oo = 0; oo < 2; ++oo)
                bw[oo] = cvt_w8(Wv + (size_t)(32 * wave + 16 * oo + l15) * C_ + quad * 8 + kh * 32);
            #pragma unroll
            for (int nt = 0; nt < 4; ++nt)
                #pragma unroll
                for (int oo = 0; oo < 2; ++oo)
                    acc[nt][oo] = __builtin_amdgcn_mfma_f32_16x16x32_f16(
                        af[nt], bw[oo], acc[nt][oo], 0, 0, 0);
        }
        #pragma unroll
        for (int oo = 0; oo < 2; ++oo) {
            int c = 32 * wave + 16 * oo + l15;
            float bv = vb[c];
            #pragma unroll
            for (int nt = 0; nt < 4; ++nt) {
                ushort4 u;
                u.x = f2bf(acc[nt][oo][0] + bv);
                u.y = f2bf(acc[nt][oo][1] + bv);
                u.z = f2bf(acc[nt][oo][2] + bv);
                u.w = f2bf(acc[nt][oo][3] + bv);
                *(ushort4*)(outp + (size_t)c * N_ + n0 + 16 * nt + quad * 4) = u;
            }
        }
    }
}

// ---------------------------------------------------------------------------
// MFMA flash attention, static-shift softmax, j-split partials, SKEWED
// pipeline: iter t runs S(t) and PV(t-1) in the same window so ds_read,
// VMEM, MFMA and exp-VALU overlap per wave (one lgkm-only barrier per iter;
// PV reads the buffer sealed by the PREVIOUS barrier).
// Exactness: shift-invariance (static SHIFT); gating bias constant along
// softmax axis -> cancels; disjoint-j partials merge by pure addition.
// grid 512 = 4 bs x 64 q-tiles x 2 j-splits.  8 waves/WG.
// ---------------------------------------------------------------------------
__global__ __launch_bounds__(512, 4)
void flash_kernel(const _Float16* __restrict__ qg,        // [bs][n][64] f16
                  const _Float16* __restrict__ kg,        // [bs][n][64] f16
                  const unsigned short* __restrict__ vg,  // [bs][c][n] bf16
                  float* __restrict__ out,                // split0 partial O
                  float* __restrict__ part1,              // split1 partial O
                  float* __restrict__ lp)                 // [2][4][4096]
{
    __shared__ unsigned short Pt[2][64 * 64];   // [i][j], 16B-chunk ^ (i&7)
    __shared__ float lsum[64 * 4];

    const int tid  = threadIdx.x;
    const int lane = tid & 63;
    const int wave = tid >> 6;                  // 0..7
    const int quad = lane >> 4;
    const int l15  = lane & 15;
    const int blk  = blockIdx.x;
    const int bs   = blk & 3;                   // XCD L2 affinity
    const int split = (blk >> 2) & 1;
    const int q0   = (blk >> 3) * 64;
    const int jbase = split * 2048;
    const int jb = wave & 3, ih = wave >> 2;    // S role
    const int wc = wave;                        // PV role: c-block 32*wc

    const _Float16* qp = qg + (size_t)bs * N_ * CQ_;
    const _Float16* kp = kg + (size_t)bs * N_ * CQ_;
    const unsigned short* vp = vg + (size_t)bs * CN;

    // persistent Q B-frags (col i = q0 + 32ih + 16isub + l15)
    half8 qf[2][2];
    #pragma unroll
    for (int isub = 0; isub < 2; ++isub)
        #pragma unroll
        for (int kh = 0; kh < 2; ++kh)
            qf[isub][kh] = *(const half8*)(
                qp + (size_t)(q0 + 32 * ih + 16 * isub + l15) * CQ_ + quad * 8 + kh * 32);

    float lacc[2] = {0.f, 0.f};
    f32x4 acc[4][2];   // [isub: i=16isub+quad*4+r][csub: c=32wc+16csub+l15]
    #pragma unroll
    for (int a = 0; a < 4; ++a)
        #pragma unroll
        for (int b = 0; b < 2; ++b) acc[a][b] = (f32x4){0.f, 0.f, 0.f, 0.f};

    // K frag for iter 0
    half8 kf[2];
    #pragma unroll
    for (int kh = 0; kh < 2; ++kh)
        kf[kh] = *(const half8*)(
            kp + (size_t)(jbase + 16 * jb + l15) * CQ_ + quad * 8 + kh * 32);
    half8 kn[2];
    short8 vf[2][2], vn[2][2];

    // ---------------- iter 0 (peeled: S only, no PV yet) ----------------
    {
        // issue K(1), V(0)
        #pragma unroll
        for (int kh = 0; kh < 2; ++kh)
            kn[kh] = *(const half8*)(
                kp + (size_t)(jbase + 64 + 16 * jb + l15) * CQ_ + quad * 8 + kh * 32);
        #pragma unroll
        for (int csub = 0; csub < 2; ++csub)
            #pragma unroll
            for (int kh = 0; kh < 2; ++kh)
                vn[csub][kh] = *(const short8*)(
                    vp + (size_t)(32 * wc + 16 * csub + l15) * N_ + jbase + quad * 8 + kh * 32);

        f32x4 sacc[2];
        sacc[0] = (f32x4){0.f, 0.f, 0.f, 0.f};
        sacc[1] = (f32x4){0.f, 0.f, 0.f, 0.f};
        #pragma unroll
        for (int kh = 0; kh < 2; ++kh)
            #pragma unroll
            for (int isub = 0; isub < 2; ++isub)
                sacc[isub] = __builtin_amdgcn_mfma_f32_16x16x32_f16(
                    kf[kh], qf[isub][kh], sacc[isub], 0, 0, 0);
        #pragma unroll
        for (int isub = 0; isub < 2; ++isub) {
            f32x4 p;
            p.x = __expf(sacc[isub].x - SHIFT);
            p.y = __expf(sacc[isub].y - SHIFT);
            p.z = __expf(sacc[isub].z - SHIFT);
            p.w = __expf(sacc[isub].w - SHIFT);
            lacc[isub] += p.x + p.y + p.z + p.w;
            ushort4 pb;
            pb.x = f2bf(p.x); pb.y = f2bf(p.y); pb.z = f2bf(p.z); pb.w = f2bf(p.w);
            int row = 32 * ih + 16 * isub + l15;
            int off = row * 64 + (((2 * jb + (quad >> 1)) ^ (row & 7)) << 3)
                    + ((quad & 1) << 2);
            *(ushort4*)(&Pt[0][off]) = pb;
        }
        asm volatile("s_waitcnt lgkmcnt(0)\n\ts_barrier" ::: "memory");
        kf[0] = kn[0]; kf[1] = kn[1];
        #pragma unroll
        for (int csub = 0; csub < 2; ++csub)
            #pragma unroll
            for (int kh = 0; kh < 2; ++kh) vf[csub][kh] = vn[csub][kh];
    }

    // ---------------- main loop: S(t) + PV(t-1) per iter ----------------
    for (int t = 1; t < 32; ++t) {
        const int jt = jbase + t * 64;
        const int jn = (t + 1 < 32) ? jt + 64 : jbase;
        // issue K(t+1), V(t) (consumed next iter; fly across the barrier)
        #pragma unroll
        for (int kh = 0; kh < 2; ++kh)
            kn[kh] = *(const half8*)(
                kp + (size_t)(jn + 16 * jb + l15) * CQ_ + quad * 8 + kh * 32);
        #pragma unroll
        for (int csub = 0; csub < 2; ++csub)
            #pragma unroll
            for (int kh = 0; kh < 2; ++kh)
                vn[csub][kh] = *(const short8*)(
                    vp + (size_t)(32 * wc + 16 * csub + l15) * N_ + jt + quad * 8 + kh * 32);

        // early ds_read of P(t-1) A-frags (buffer sealed by previous barrier)
        const unsigned short* Rb = Pt[(t & 1) ^ 1];
        short8 ap[4][2];
        #pragma unroll
        for (int isub = 0; isub < 4; ++isub)
            #pragma unroll
            for (int kh = 0; kh < 2; ++kh) {
                int row = 16 * isub + l15;
                ap[isub][kh] = *(const short8*)(
                    &Rb[row * 64 + (((quad + 4 * kh) ^ (row & 7)) << 3)]);
            }

        // ---- S(t): S^T[j=16jb+quad*4+r][i=32ih+16isub+l15] ----
        f32x4 sacc[2];
        sacc[0] = (f32x4){0.f, 0.f, 0.f, 0.f};
        sacc[1] = (f32x4){0.f, 0.f, 0.f, 0.f};
        #pragma unroll
        for (int kh = 0; kh < 2; ++kh)
            #pragma unroll
            for (int isub = 0; isub < 2; ++isub)
                sacc[isub] = __builtin_amdgcn_mfma_f32_16x16x32_f16(
                    kf[kh], qf[isub][kh], sacc[isub], 0, 0, 0);

        // exp -> bf16 -> write P(t) into the OTHER buffer
        unsigned short* Wb = Pt[t & 1];
        #pragma unroll
        for (int isub = 0; isub < 2; ++isub) {
            f32x4 p;
            p.x = __expf(sacc[isub].x - SHIFT);
            p.y = __expf(sacc[isub].y - SHIFT);
            p.z = __expf(sacc[isub].z - SHIFT);
            p.w = __expf(sacc[isub].w - SHIFT);
            lacc[isub] += p.x + p.y + p.z + p.w;
            ushort4 pb;
            pb.x = f2bf(p.x); pb.y = f2bf(p.y); pb.z = f2bf(p.z); pb.w = f2bf(p.w);
            int row = 32 * ih + 16 * isub + l15;
            int off = row * 64 + (((2 * jb + (quad >> 1)) ^ (row & 7)) << 3)
                    + ((quad & 1) << 2);
            *(ushort4*)(&Wb[off]) = pb;
        }

        // ---- PV(t-1): acc += P(t-1) x V(t-1) ----
        #pragma unroll
        for (int kh = 0; kh < 2; ++kh)
            #pragma unroll
            for (int isub = 0; isub < 4; ++isub)
                #pragma unroll
                for (int csub = 0; csub < 2; ++csub)
                    acc[isub][csub] = __builtin_amdgcn_mfma_f32_16x16x32_bf16(
                        ap[isub][kh], vf[csub][kh], acc[isub][csub], 0, 0, 0);

        // LDS-only barrier: no vmcnt drain (K/V prefetch stays in flight)
        asm volatile("s_waitcnt lgkmcnt(0)\n\ts_barrier" ::: "memory");

        kf[0] = kn[0]; kf[1] = kn[1];
        #pragma unroll
        for (int csub = 0; csub < 2; ++csub)
            #pragma unroll
            for (int kh = 0; kh < 2; ++kh) vf[csub][kh] = vn[csub][kh];
    }

    // ---------------- epilogue: PV(31) ----------------
    {
        const unsigned short* Rb = Pt[1];
        short8 ap[4][2];
        #pragma unroll
        for (int isub = 0; isub < 4; ++isub)
            #pragma unroll
            for (int kh = 0; kh < 2; ++kh) {
                int row = 16 * isub + l15;
                ap[isub][kh] = *(const short8*)(
                    &Rb[row * 64 + (((quad + 4 * kh) ^ (row & 7)) << 3)]);
            }
        #pragma unroll
        for (int kh = 0; kh < 2; ++kh)
            #pragma unroll
            for (int isub = 0; isub < 4; ++isub)
                #pragma unroll
                for (int csub = 0; csub < 2; ++csub)
                    acc[isub][csub] = __builtin_amdgcn_mfma_f32_16x16x32_bf16(
                        ap[isub][kh], vf[csub][kh], acc[isub][csub], 0, 0, 0);
    }

    // ---- partial l reduction ----
    #pragma unroll
    for (int isub = 0; isub < 2; ++isub) {
        float tq = lacc[isub];
        tq += __shfl_xor(tq, 16);
        tq += __shfl_xor(tq, 32);
        if (quad == 0) lsum[(32 * ih + 16 * isub + l15) * 4 + jb] = tq;
    }
    __syncthreads();
    if (tid < 64) {
        f32x4 tl = *(f32x4*)(&lsum[tid * 4]);
        lp[(size_t)(split * 4 + bs) * N_ + q0 + tid] = tl.x + tl.y + tl.z + tl.w;
    }

    // ---- raw partial-O store (fp32, unnormalized, no input add) ----
    float* pp = (split ? part1 : out) + (size_t)bs * CN;
    #pragma unroll
    for (int isub = 0; isub < 4; ++isub)
        #pragma unroll
        for (int csub = 0; csub < 2; ++csub) {
            int c = 32 * wc + 16 * csub + l15;
            int i0 = q0 + 16 * isub + quad * 4;
            f32x4 a = acc[isub][csub];
            float4 o4 = {a[0], a[1], a[2], a[3]};
            *(float4*)(pp + (size_t)c * N_ + i0) = o4;
        }
}

// ---------------------------------------------------------------------------
// Merge: out = gamma * (O0 + O1) / (l0 + l1) + input
// ---------------------------------------------------------------------------
__global__ __launch_bounds__(256)
void merge_kernel(const float* __restrict__ part1, const float* __restrict__ lp,
                  const float* __restrict__ in1, const float* __restrict__ in2,
                  const float* __restrict__ gamma_p, float* __restrict__ out)
{
    const int g = (blockIdx.x * 256 + threadIdx.x) * 4;   // grid 4096
    const int bs = g >> 20;                                // CN = 1<<20
    const int off = g & (CN - 1);
    const int i = g & (N_ - 1);
    const float gamma = gamma_p[0];
    float4 o0 = *(const float4*)(out + g);
    float4 p1 = *(const float4*)(part1 + g);
    float4 l0 = *(const float4*)(lp + (size_t)bs * N_ + i);
    float4 l1 = *(const float4*)(lp + (size_t)(4 + bs) * N_ + i);
    const float* inp = ((bs >> 1) ? in2 : in1) + (size_t)(bs & 1) * CN;
    float4 ip = *(const float4*)(inp + off);
    float4 r;
    r.x = gamma * (o0.x + p1.x) / (l0.x + l1.x) + ip.x;
    r.y = gamma * (o0.y + p1.y) / (l0.y + l1.y) + ip.y;
    r.z = gamma * (o0.z + p1.z) / (l0.z + l1.z) + ip.z;
    r.w = gamma * (o0.w + p1.w) / (l0.w + l1.w) + ip.w;
    *(float4*)(out + g) = r;
}

// ---------------------------------------------------------------------------
extern "C" void kernel_launch(void* const* d_in, const int* in_sizes, int n_in,
                              void* d_out, int out_size, void* d_ws, size_t ws_size,
                              hipStream_t stream)
{
    const float* in1 = (const float*)d_in[0];
    const float* in2 = (const float*)d_in[1];
    const float* q1w = (const float*)d_in[2];
    const float* q1b = (const float*)d_in[3];
    const float* k1w = (const float*)d_in[4];
    const float* k1b = (const float*)d_in[5];
    const float* v1w = (const float*)d_in[6];
    const float* v1b = (const float*)d_in[7];
    const float* q2w = (const float*)d_in[8];
    const float* q2b = (const float*)d_in[9];
    const float* k2w = (const float*)d_in[10];
    const float* k2b = (const float*)d_in[11];
    const float* v2w = (const float*)d_in[12];
    const float* v2b = (const float*)d_in[13];
    const float* gamma = (const float*)d_in[22];
    float* out = (float*)d_out;

    // ws: q 2MB f16 | k 2MB f16 | v 8MB bf16 | part1 16.8MB fp32 | lp 128KB
    _Float16* q_ws = (_Float16*)d_ws;
    _Float16* k_ws = q_ws + (size_t)4 * N_ * CQ_;
    unsigned short* v_ws = (unsigned short*)(k_ws + (size_t)4 * N_ * CQ_);
    float* part1 = (float*)(v_ws + (size_t)4 * CN);
    float* lp    = part1 + (size_t)4 * CN;

    proj_kernel<<<dim3(64, 4, 2), 512, 0, stream>>>(
        in1, in2, q1w, q1b, k1w, k1b, v1w, v1b,
        q2w, q2b, k2w, k2b, v2w, v2b, q_ws, k_ws, v_ws);
    flash_kernel<<<dim3(512), 512, 0, stream>>>(q_ws, k_ws, v_ws, out, part1, lp);
    merge_kernel<<<dim3(4096), 256, 0, stream>>>(part1, lp, in1, in2, gamma, out);
}